// Round 1
// baseline (31224.139 us; speedup 1.0000x reference)
//
#include <hip/hip_runtime.h>
#include <hip/hip_bf16.h>
#include <math.h>
#include <float.h>

#define B_Q   1024
#define N_M   50000
#define DIM   256
#define ATOMS 200
#define KSEL  8
#define NCHUNK 40
#define CHUNK  1250       // N_M / NCHUNK exactly
#define MT    128
#define NMT   10          // CHUNK/MT rounded up
#define CPC   8           // candidates kept per (query, chunk)
#define NC    (NCHUNK * CPC)   // 320 candidates per query
#define T16   16          // finalize rescore set
#define TROWS 64          // transform rows per block
#define APX   264         // A-plane LDS row stride in bf16 elems (528B, 16B-aligned)

typedef __attribute__((ext_vector_type(8))) short bf16x8;
typedef __attribute__((ext_vector_type(4))) float f32x4;

static __device__ inline unsigned short f2bf(float f) {
  __hip_bfloat16 h = __float2bfloat16(f);   // RNE
  return *reinterpret_cast<unsigned short*>(&h);
}

// RNE 3-way split (one-time W prep): x ~= s1+s2+s3, residual <= 2^-27 |x|
static __device__ inline void split3(float x, unsigned short& s1,
                                     unsigned short& s2, unsigned short& s3) {
  __hip_bfloat16 b1 = __float2bfloat16(x);
  float f1 = __bfloat162float(b1);
  float r1 = x - f1;
  __hip_bfloat16 b2 = __float2bfloat16(r1);
  float f2 = __bfloat162float(b2);
  __hip_bfloat16 b3 = __float2bfloat16(r1 - f2);
  s1 = *reinterpret_cast<unsigned short*>(&b1);
  s2 = *reinterpret_cast<unsigned short*>(&b2);
  s3 = *reinterpret_cast<unsigned short*>(&b3);
}

// Truncation 3-way split (hot path, 2 VALU/tier): residual <= 2^-24 |x|.
// x - trunc16(x) is exact (Sterbenz). Combined with RNE W tiers, dropped
// cross terms ~1e-7 rel — under the 5e-7 z-error budget.
static __device__ inline void split3t(float x, unsigned short& s1,
                                      unsigned short& s2, unsigned short& s3) {
  const unsigned u = __float_as_uint(x);
  s1 = (unsigned short)(u >> 16);
  const float f1 = __uint_as_float(u & 0xffff0000u);
  const float r1 = x - f1;                       // exact
  const unsigned v = __float_as_uint(r1);
  s2 = (unsigned short)(v >> 16);
  const float f2 = __uint_as_float(v & 0xffff0000u);
  const float r2 = r1 - f2;                      // exact
  s3 = (unsigned short)(__float_as_uint(r2) >> 16);
}

// fp32 tanh via HW v_exp_f32 (~1ulp): rel err ~1.5e-7.
static __device__ inline float tanh32(float z) {
  float tz = fabsf(z) * 2.885390082f;           // 2|z|*log2(e)
  tz = fminf(tz, 120.f);
  const float E = __builtin_amdgcn_exp2f(tz);   // e^{2|z|}
  const float T = 1.f - 2.f / (E + 1.f);
  return (z >= 0.f) ? T : -T;
}

// ---------------------------------------------------------------------------
// W pre-split: Wt planes [n][k] (transposed) as bf16 triple. 256x256, tiny.
// ---------------------------------------------------------------------------
__global__ __launch_bounds__(256) void wsplit_kernel(
    const float* __restrict__ W,
    unsigned short* __restrict__ Wt1, unsigned short* __restrict__ Wt2,
    unsigned short* __restrict__ Wt3)
{
  const int n = blockIdx.x;
  const int k = threadIdx.x;
  unsigned short s1, s2, s3;
  split3(W[(size_t)k * DIM + n], s1, s2, s3);
  Wt1[(size_t)n * DIM + k] = s1;
  Wt2[(size_t)n * DIM + k] = s2;
  Wt3[(size_t)n * DIM + k] = s3;
}

// ---------------------------------------------------------------------------
// Transform: H = to_poincare(X @ W + b); X@W via bf16 MFMA, 3-way Dekker
// split (6 product orders) chained into one fp32 accumulator per m-subtile.
// Block = 64 rows x 1024 threads (16 waves); wave w owns output cols
// [16w,16w+16): Wt is read ONCE per block (24 b128 loads/wave, explicit
// ks+1 double-buffer), A-planes staged in LDS (101KB, truncation splits,
// b128 writes). Per ks: 3 B-loads + 12 A ds_reads + 24 MFMA.
// MFMA layouts (HW-verified here through 4 passing rounds):
// A[m=lane&15][k=quad*8+j], B[n=lane&15][k=quad*8+j], D col=lane&15
// row=quad*4+reg. Epilogue fp32: tanh, 2-level row-norm reduce, scale, aux.
// ---------------------------------------------------------------------------
__global__ __launch_bounds__(1024) void transform_kernel(
    const float* __restrict__ X, int nrows,
    const unsigned short* __restrict__ Wt1, const unsigned short* __restrict__ Wt2,
    const unsigned short* __restrict__ Wt3, const float* __restrict__ bvec,
    float* __restrict__ H, unsigned short* __restrict__ Hb,
    float2* __restrict__ aux)
{
  __shared__ __align__(16) unsigned short X1s[TROWS * APX];
  __shared__ __align__(16) unsigned short X2s[TROWS * APX];
  __shared__ __align__(16) unsigned short X3s[TROWS * APX];
  __shared__ float red[16][TROWS];
  __shared__ float sArr[TROWS];

  const int t    = threadIdx.x;
  const int lane = t & 63;
  const int wave = t >> 6;
  const int row0 = blockIdx.x * TROWS;

  // stage + split X tile [64][256]: thread owns (row r, 16 cols at c0)
  {
    const int r  = t >> 4;
    const int c0 = (t & 15) * 16;
    int gr = row0 + r; if (gr >= nrows) gr = nrows - 1;   // clamp (stores guarded)
    const float4* src = (const float4*)(X + (size_t)gr * DIM + c0);
    bf16x8 p1[2], p2[2], p3[2];
#pragma unroll
    for (int half = 0; half < 2; ++half) {
#pragma unroll
      for (int v = 0; v < 2; ++v) {
        const float4 x4 = src[half * 2 + v];
        const float xv[4] = {x4.x, x4.y, x4.z, x4.w};
#pragma unroll
        for (int i = 0; i < 4; ++i) {
          unsigned short s1, s2, s3;
          split3t(xv[i], s1, s2, s3);
          p1[half][v * 4 + i] = (short)s1;
          p2[half][v * 4 + i] = (short)s2;
          p3[half][v * 4 + i] = (short)s3;
        }
      }
      *(bf16x8*)(X1s + r * APX + c0 + half * 8) = p1[half];
      *(bf16x8*)(X2s + r * APX + c0 + half * 8) = p2[half];
      *(bf16x8*)(X3s + r * APX + c0 + half * 8) = p3[half];
    }
  }
  __syncthreads();

  const int lx   = lane & 15;    // A row m / B col n / D col
  const int quad = lane >> 4;    // k-group / D row-quad
  const int n0   = wave * 16;    // this wave's output col-tile

  f32x4 acc[4];
#pragma unroll
  for (int ms = 0; ms < 4; ++ms) { acc[ms][0] = 0.f; acc[ms][1] = 0.f; acc[ms][2] = 0.f; acc[ms][3] = 0.f; }

  const size_t brow = (size_t)(n0 + lx) * DIM + quad * 8;
  bf16x8 b1c = *(const bf16x8*)(Wt1 + brow);
  bf16x8 b2c = *(const bf16x8*)(Wt2 + brow);
  bf16x8 b3c = *(const bf16x8*)(Wt3 + brow);

#pragma unroll
  for (int ks = 0; ks < 8; ++ks) {
    bf16x8 b1n, b2n, b3n;
    if (ks < 7) {                       // prefetch next k-step's B
      const size_t nb = brow + (ks + 1) * 32;
      b1n = *(const bf16x8*)(Wt1 + nb);
      b2n = *(const bf16x8*)(Wt2 + nb);
      b3n = *(const bf16x8*)(Wt3 + nb);
    }
    const int ko = ks * 32 + quad * 8;
#pragma unroll
    for (int ms = 0; ms < 4; ++ms) {
      const int ar = (ms * 16 + lx) * APX + ko;
      const bf16x8 a1 = *(const bf16x8*)(X1s + ar);
      const bf16x8 a2 = *(const bf16x8*)(X2s + ar);
      const bf16x8 a3 = *(const bf16x8*)(X3s + ar);
      acc[ms] = __builtin_amdgcn_mfma_f32_16x16x32_bf16(a1, b1c, acc[ms], 0, 0, 0);
      acc[ms] = __builtin_amdgcn_mfma_f32_16x16x32_bf16(a1, b2c, acc[ms], 0, 0, 0);
      acc[ms] = __builtin_amdgcn_mfma_f32_16x16x32_bf16(a2, b1c, acc[ms], 0, 0, 0);
      acc[ms] = __builtin_amdgcn_mfma_f32_16x16x32_bf16(a1, b3c, acc[ms], 0, 0, 0);
      acc[ms] = __builtin_amdgcn_mfma_f32_16x16x32_bf16(a2, b2c, acc[ms], 0, 0, 0);
      acc[ms] = __builtin_amdgcn_mfma_f32_16x16x32_bf16(a3, b1c, acc[ms], 0, 0, 0);
    }
    b1c = b1n; b2c = b2n; b3c = b3n;
  }

  // bias + tanh: lane holds rows ms*16+quad*4+r, col n0+lx (bias col-constant)
  const float bb = bvec[n0 + lx];
  float h[4][4];
#pragma unroll
  for (int ms = 0; ms < 4; ++ms)
#pragma unroll
    for (int r = 0; r < 4; ++r)
      h[ms][r] = tanh32(acc[ms][r] + bb);

  // row-norm partial over this wave's 16 cols (shuffle over lx)
  float p[4][4];
#pragma unroll
  for (int ms = 0; ms < 4; ++ms)
#pragma unroll
    for (int r = 0; r < 4; ++r) p[ms][r] = h[ms][r] * h[ms][r];
#pragma unroll
  for (int off = 1; off < 16; off <<= 1)
#pragma unroll
    for (int ms = 0; ms < 4; ++ms)
#pragma unroll
      for (int r = 0; r < 4; ++r) p[ms][r] += __shfl_xor(p[ms][r], off);
  if (lx == 0)
#pragma unroll
    for (int ms = 0; ms < 4; ++ms)
#pragma unroll
      for (int r = 0; r < 4; ++r) red[wave][ms * 16 + quad * 4 + r] = p[ms][r];
  __syncthreads();

  if (t < TROWS) {
    float nsq = 0.f;
#pragma unroll
    for (int w = 0; w < 16; ++w) nsq += red[w][t];
    const float nrm = sqrtf(nsq);
    sArr[t] = (nrm > 0.95f) ? (0.95f / nrm) : 1.f;
  }
  __syncthreads();

  float u[4][4];
#pragma unroll
  for (int ms = 0; ms < 4; ++ms)
#pragma unroll
    for (int r = 0; r < 4; ++r) {
      const float sc = sArr[ms * 16 + quad * 4 + r];
      u[ms][r] = h[ms][r] * sc;
      p[ms][r] = u[ms][r] * u[ms][r];
    }
#pragma unroll
  for (int off = 1; off < 16; off <<= 1)
#pragma unroll
    for (int ms = 0; ms < 4; ++ms)
#pragma unroll
      for (int r = 0; r < 4; ++r) p[ms][r] += __shfl_xor(p[ms][r], off);
  if (lx == 0)
#pragma unroll
    for (int ms = 0; ms < 4; ++ms)
#pragma unroll
      for (int r = 0; r < 4; ++r) red[wave][ms * 16 + quad * 4 + r] = p[ms][r];

  // stores: H fp32 + Hb bf16 (guarded rows)
#pragma unroll
  for (int ms = 0; ms < 4; ++ms)
#pragma unroll
    for (int r = 0; r < 4; ++r) {
      const int grow = row0 + ms * 16 + quad * 4 + r;
      if (grow < nrows) {
        H[(size_t)grow * DIM + n0 + lx]  = u[ms][r];
        Hb[(size_t)grow * DIM + n0 + lx] = f2bf(u[ms][r]);
      }
    }
  __syncthreads();
  if (t < TROWS) {
    const int grow = row0 + t;
    if (grow < nrows) {
      float ysq = 0.f;
#pragma unroll
      for (int w = 0; w < 16; ++w) ysq += red[w][t];
      aux[grow] = make_float2(ysq, 1.f / (1.f - ysq));
    }
  }
}

// ---------------------------------------------------------------------------
// Score (MFMA), v2: barrier-free independent waves.
// Block = 32 queries x 1 chunk, 4 waves. Grid (chunk, qtile): linear id
// = c + 40*q -> XCD (id%8) = c%8, chunk's 640KB Hmb stays in one XCD's L2.
// Each wave independently owns m-rows {mt*128 + wave*32 + 0..31}: per mtile
// it loads B (two batches of 8 b128 frags to cap VGPR), runs 32 MFMA off
// the shared Afs LDS fragments, and inserts the 16 resulting scores
// (2qs x 2ms x 4r) DIRECTLY from the accumulator into per-lane sorted
// top-3 lists per query-row (quad = query-row group; the 16 lx lanes of a
// quad jointly see all 32 m-cols). No Sc LDS round-trip, no per-mtile
// barriers -> waves in different blocks/phases overlap VALU/LDS/MFMA/L2.
// Chunk-tail cols masked (col < rem) so padded-garbage rows can't win.
// Safety: a true global-top-8 entry is lost only if >=3 of the top-8 land
// in one lane's 20-value subset (E ~ 5e-6 over the whole problem at L=3).
// End: per-wave 16-lane u64 butterfly -> wave top-8/query -> one barrier ->
// 8-thread cross-wave merge of 4x8 -> exact per-(query,chunk) top-8.
// Selection score s = max(xsq+ysq-2*dot,0)/(1-ysq) is per-query monotone
// with the hyperbolic distance; fp64 rescore in finalize fixes exact order.
// ---------------------------------------------------------------------------
__global__ __launch_bounds__(256, 3) void score_kernel(
    const unsigned short* __restrict__ Hqb, const unsigned short* __restrict__ Hmb,
    const float2* __restrict__ auxq, const float2* __restrict__ auxm,
    float* __restrict__ cand_s, int* __restrict__ cand_i)
{
  __shared__ __align__(16) unsigned short Afs[16 * 64 * 8]; // 16 KB, frag-order
  __shared__ unsigned long long wtop[4][32][CPC];           // 8 KB

  const int t    = threadIdx.x;
  const int lane = t & 63;
  const int wave = t >> 6;
  const int q0   = blockIdx.y * 32;
  const int c    = blockIdx.x;
  const int mbase = c * CHUNK;
  const int lx   = lane & 15;
  const int quad = lane >> 4;

  // stage A fragments into LDS (slot = ks*2+qs; each wave stages 4 slots)
#pragma unroll
  for (int i = 0; i < 4; ++i) {
    const int sl = wave * 4 + i;
    const int ks = sl >> 1, qs = sl & 1;
    const bf16x8 a = *(const bf16x8*)(Hqb + (size_t)(q0 + qs * 16 + lx) * DIM + ks * 32 + quad * 8);
    *(bf16x8*)(Afs + ((size_t)sl * 64 + lane) * 8) = a;
  }
  float xq[2][4];
#pragma unroll
  for (int qs = 0; qs < 2; ++qs)
#pragma unroll
    for (int r = 0; r < 4; ++r)
      xq[qs][r] = auxq[q0 + qs * 16 + quad * 4 + r].x;
  __syncthreads();          // the ONLY pre-merge barrier

  // per-lane sorted top-3 per query-row (row = qs*4+r); ascending
  float tS[8][3];
  int   tI[8][3];
#pragma unroll
  for (int j = 0; j < 8; ++j) {
    tS[j][0] = FLT_MAX; tS[j][1] = FLT_MAX; tS[j][2] = FLT_MAX;
    tI[j][0] = 0; tI[j][1] = 0; tI[j][2] = 0;
  }

  const int col0 = wave * 32 + lx;   // within-128-tile column, ms=0

  for (int mt = 0; mt < NMT; ++mt) {
    const int mrow0 = mbase + mt * MT + wave * 32;
    const int rem   = CHUNK - mt * MT;       // >= 98; only mt=9 masks anything
    const bool ok0  = col0 < rem;
    const bool ok1  = col0 + 16 < rem;

    f32x4 acc[2][2];
#pragma unroll
    for (int qs = 0; qs < 2; ++qs)
#pragma unroll
      for (int ms = 0; ms < 2; ++ms) { acc[qs][ms][0] = 0.f; acc[qs][ms][1] = 0.f;
                                       acc[qs][ms][2] = 0.f; acc[qs][ms][3] = 0.f; }

    const float2 aux0 = auxm[mrow0 + lx];
    const float2 aux1 = auxm[mrow0 + 16 + lx];

    // batch 1: ks 0..3
    bf16x8 b0[4], b1[4];
#pragma unroll
    for (int ks = 0; ks < 4; ++ks) {
      b0[ks] = *(const bf16x8*)(Hmb + (size_t)(mrow0 + lx)      * DIM + ks * 32 + quad * 8);
      b1[ks] = *(const bf16x8*)(Hmb + (size_t)(mrow0 + 16 + lx) * DIM + ks * 32 + quad * 8);
    }
#pragma unroll
    for (int ks = 0; ks < 4; ++ks) {
      const bf16x8 a0 = *(const bf16x8*)(Afs + ((size_t)(ks * 2 + 0) * 64 + lane) * 8);
      const bf16x8 a1 = *(const bf16x8*)(Afs + ((size_t)(ks * 2 + 1) * 64 + lane) * 8);
      acc[0][0] = __builtin_amdgcn_mfma_f32_16x16x32_bf16(a0, b0[ks], acc[0][0], 0, 0, 0);
      acc[0][1] = __builtin_amdgcn_mfma_f32_16x16x32_bf16(a0, b1[ks], acc[0][1], 0, 0, 0);
      acc[1][0] = __builtin_amdgcn_mfma_f32_16x16x32_bf16(a1, b0[ks], acc[1][0], 0, 0, 0);
      acc[1][1] = __builtin_amdgcn_mfma_f32_16x16x32_bf16(a1, b1[ks], acc[1][1], 0, 0, 0);
    }
    // batch 2: ks 4..7 (reuses b regs; latency covered by co-resident waves)
#pragma unroll
    for (int ks = 4; ks < 8; ++ks) {
      b0[ks - 4] = *(const bf16x8*)(Hmb + (size_t)(mrow0 + lx)      * DIM + ks * 32 + quad * 8);
      b1[ks - 4] = *(const bf16x8*)(Hmb + (size_t)(mrow0 + 16 + lx) * DIM + ks * 32 + quad * 8);
    }
#pragma unroll
    for (int ks = 4; ks < 8; ++ks) {
      const bf16x8 a0 = *(const bf16x8*)(Afs + ((size_t)(ks * 2 + 0) * 64 + lane) * 8);
      const bf16x8 a1 = *(const bf16x8*)(Afs + ((size_t)(ks * 2 + 1) * 64 + lane) * 8);
      acc[0][0] = __builtin_amdgcn_mfma_f32_16x16x32_bf16(a0, b0[ks - 4], acc[0][0], 0, 0, 0);
      acc[0][1] = __builtin_amdgcn_mfma_f32_16x16x32_bf16(a0, b1[ks - 4], acc[0][1], 0, 0, 0);
      acc[1][0] = __builtin_amdgcn_mfma_f32_16x16x32_bf16(a1, b0[ks - 4], acc[1][0], 0, 0, 0);
      acc[1][1] = __builtin_amdgcn_mfma_f32_16x16x32_bf16(a1, b1[ks - 4], acc[1][1], 0, 0, 0);
    }

    // scores straight from the accumulator -> per-lane top-3 insert
#pragma unroll
    for (int qs = 0; qs < 2; ++qs)
#pragma unroll
      for (int ms = 0; ms < 2; ++ms) {
        const float ym = ms ? aux1.x : aux0.x;
        const float ro = ms ? aux1.y : aux0.y;
        const bool ok  = ms ? ok1 : ok0;
        const int  gi  = mrow0 + ms * 16 + lx;   // global memory index
#pragma unroll
        for (int r = 0; r < 4; ++r) {
          const float sv = fmaxf(fmaf(-2.f, acc[qs][ms][r], xq[qs][r] + ym), 0.f) * ro;
          const int row = qs * 4 + r;
          if (ok && sv < tS[row][2]) {
            tS[row][2] = sv; tI[row][2] = gi;
            if (tS[row][2] < tS[row][1]) { float a = tS[row][1]; tS[row][1] = tS[row][2]; tS[row][2] = a;
                                           int   b = tI[row][1]; tI[row][1] = tI[row][2]; tI[row][2] = b; }
            if (tS[row][1] < tS[row][0]) { float a = tS[row][0]; tS[row][0] = tS[row][1]; tS[row][1] = a;
                                           int   b = tI[row][0]; tI[row][0] = tI[row][1]; tI[row][1] = b; }
          }
        }
      }
  }

  // per-wave extraction: per query-row, 16 lanes x top-3 -> wave top-8
  // (quads process 4 different query-rows in parallel; offsets 1..8 stay
  //  within a quad). Packed (score,idx) u64 -> unique keys, stable ties.
#pragma unroll
  for (int qs = 0; qs < 2; ++qs)
#pragma unroll
    for (int r = 0; r < 4; ++r) {
      const int row = qs * 4 + r;
      unsigned long long p0 = (((unsigned long long)__float_as_uint(tS[row][0])) << 32) | (unsigned int)tI[row][0];
      unsigned long long p1 = (((unsigned long long)__float_as_uint(tS[row][1])) << 32) | (unsigned int)tI[row][1];
      unsigned long long p2 = (((unsigned long long)__float_as_uint(tS[row][2])) << 32) | (unsigned int)tI[row][2];
      for (int rd = 0; rd < CPC; ++rd) {
        unsigned long long lm = (p0 < p1) ? p0 : p1;
        lm = (p2 < lm) ? p2 : lm;
        unsigned long long gm = lm;
#pragma unroll
        for (int off = 1; off < 16; off <<= 1) {
          const unsigned long long o = __shfl_xor(gm, off);
          gm = (o < gm) ? o : gm;
        }
        if      (p0 == gm) p0 = ~0ULL;
        else if (p1 == gm) p1 = ~0ULL;
        else if (p2 == gm) p2 = ~0ULL;
        if (lx == 0) wtop[wave][qs * 16 + quad * 4 + r][rd] = gm;
      }
    }
  __syncthreads();

  // cross-wave merge: 8 threads per query, 4 waves x 8 -> top-8 -> cand
  {
    const int qr = t >> 3;        // 0..31
    const int sp = t & 7;
    unsigned long long v0 = wtop[0][qr][sp];
    unsigned long long v1 = wtop[1][qr][sp];
    unsigned long long v2 = wtop[2][qr][sp];
    unsigned long long v3 = wtop[3][qr][sp];
    const size_t cbase = ((size_t)(q0 + qr) * NCHUNK + c) * CPC;
    for (int rd = 0; rd < CPC; ++rd) {
      unsigned long long lm = (v0 < v1) ? v0 : v1;
      const unsigned long long l2 = (v2 < v3) ? v2 : v3;
      lm = (l2 < lm) ? l2 : lm;
      unsigned long long gm = lm;
#pragma unroll
      for (int off = 1; off < 8; off <<= 1) {
        const unsigned long long o = __shfl_xor(gm, off);
        gm = (o < gm) ? o : gm;
      }
      if      (v0 == gm) v0 = ~0ULL;
      else if (v1 == gm) v1 = ~0ULL;
      else if (v2 == gm) v2 = ~0ULL;
      else if (v3 == gm) v3 = ~0ULL;
      if (sp == 0) {
        cand_s[cbase + rd] = __uint_as_float((unsigned int)(gm >> 32));
        cand_i[cbase + rd] = (int)(unsigned int)(gm & 0xffffffffu);
      }
    }
  }
}

// ---------------------------------------------------------------------------
// Finalize: per query, 256 threads (4 waves): parallel candidate merge
// 320 -> 4x16 -> top-16 (fp32 score, idx tie-break), fp64 rescore (4 cands
// per wave) -> exact top-8 order, softmax, parallel mask gather.
// ---------------------------------------------------------------------------
__global__ __launch_bounds__(256) void finalize_kernel(
    const float* __restrict__ Hq, const float* __restrict__ Hm,
    const float* __restrict__ masks,
    const float* __restrict__ cand_s, const int* __restrict__ cand_i,
    float* __restrict__ outW, float* __restrict__ outH)
{
  const int q    = blockIdx.x;
  const int t    = threadIdx.x;
  const int lane = t & 63;
  const int wave = t >> 6;

  __shared__ unsigned long long wtop[4][T16];
  __shared__ int    selIdx[T16];
  __shared__ double dArr[T16];
  __shared__ int    fin_i[KSEL];
  __shared__ double fin_d[KSEL];
  __shared__ double ew[KSEL];

  // phase 1: each wave takes 80 candidates -> its top-16 (indices unique)
  {
    const size_t base = (size_t)q * NC + (size_t)wave * (NC / 4);
    unsigned long long pk[2];
#pragma unroll
    for (int s = 0; s < 2; ++s) {
      const int c = lane + 64 * s;
      pk[s] = (c < NC / 4)
        ? ((((unsigned long long)__float_as_uint(cand_s[base + c])) << 32) | (unsigned int)cand_i[base + c])
        : ~0ULL;
    }
    for (int r = 0; r < T16; ++r) {
      unsigned long long lm = (pk[0] < pk[1]) ? pk[0] : pk[1];
      unsigned long long gm = lm;
#pragma unroll
      for (int off = 1; off < 64; off <<= 1) {
        unsigned long long o = __shfl_xor(gm, off);
        gm = (o < gm) ? o : gm;
      }
      bool done = false;
#pragma unroll
      for (int s = 0; s < 2; ++s) if (!done && pk[s] == gm) { pk[s] = ~0ULL; done = true; }
      if (lane == 0) wtop[wave][r] = gm;
    }
  }
  __syncthreads();

  // phase 2: wave 0 merges 64 -> global top-16
  if (wave == 0) {
    unsigned long long v = wtop[lane >> 4][lane & 15];
    for (int r = 0; r < T16; ++r) {
      unsigned long long gm = v;
#pragma unroll
      for (int off = 1; off < 64; off <<= 1) {
        unsigned long long o = __shfl_xor(gm, off);
        gm = (o < gm) ? o : gm;
      }
      if (v == gm) v = ~0ULL;
      if (lane == 0) selIdx[r] = (int)(unsigned int)(gm & 0xffffffffULL);
    }
  }
  __syncthreads();

  // phase 3: fp64 rescore, 4 candidates per wave
  const float4 q4 = *(const float4*)(Hq + (size_t)q * DIM + 4 * lane);
  double xp_ = (double)q4.x * q4.x + (double)q4.y * q4.y + (double)q4.z * q4.z + (double)q4.w * q4.w;
#pragma unroll
  for (int off = 1; off < 64; off <<= 1) xp_ += __shfl_xor(xp_, off);
  const double xsq = xp_;

  for (int r = wave; r < T16; r += 4) {
    const int cidx = selIdx[r];
    const float4 m4 = *(const float4*)(Hm + (size_t)cidx * DIM + 4 * lane);
    double dp = (double)q4.x * m4.x + (double)q4.y * m4.y + (double)q4.z * m4.z + (double)q4.w * m4.w;
    double yp = (double)m4.x * m4.x + (double)m4.y * m4.y + (double)m4.z * m4.z + (double)m4.w * m4.w;
#pragma unroll
    for (int off = 1; off < 64; off <<= 1) { dp += __shfl_xor(dp, off); yp += __shfl_xor(yp, off); }
    if (lane == 0) {
      double diff = xsq + yp - 2.0 * dp; if (diff < 0.0) diff = 0.0;
      double den = (1.0 - xsq) * (1.0 - yp);
      double arg = 1.0 + 2.0 * diff / (den + 1e-8);
      const double lo = 1.0 + 1e-6;
      if (arg < lo) arg = lo;
      dArr[r] = log(arg + sqrt(arg * arg - 1.0));   // arccosh
    }
  }
  __syncthreads();

  // phase 4: exact rank (dist, idx) -> top-8, softmax
  if (t < T16) {
    const double dj = dArr[t]; const int ij = selIdx[t];
    int rank = 0;
#pragma unroll
    for (int i = 0; i < T16; ++i)
      rank += (dArr[i] < dj || (dArr[i] == dj && selIdx[i] < ij)) ? 1 : 0;
    if (rank < KSEL) { fin_d[rank] = dj; fin_i[rank] = ij; }
  }
  __syncthreads();
  if (t < KSEL) ew[t] = exp(fin_d[0] - fin_d[t]);
  __syncthreads();
  if (t < KSEL) {
    double ssum = 0.0;
#pragma unroll
    for (int i = 0; i < KSEL; ++i) ssum += ew[i];
    outW[(size_t)q * KSEL + t] = (float)(ew[t] / ssum);
  }

  // phase 5: mask gather, 32 threads per output row
  const int g  = t >> 5;
  const int l0 = t & 31;
  const int row = fin_i[g];
  for (int l = l0; l < ATOMS; l += 32)
    outH[((size_t)q * KSEL + g) * ATOMS + l] = masks[(size_t)row * ATOMS + l];
}

// ---------------------------------------------------------------------------
extern "C" void kernel_launch(void* const* d_in, const int* in_sizes, int n_in,
                              void* d_out, int out_size, void* d_ws, size_t ws_size,
                              hipStream_t stream) {
  const float* Q     = (const float*)d_in[0];   // [1024,256]
  const float* M     = (const float*)d_in[1];   // [50000,256]
  const float* masks = (const float*)d_in[2];   // [50000,200]
  const float* W     = (const float*)d_in[3];   // [256,256]
  const float* bv    = (const float*)d_in[4];   // [256]
  // d_in[5] = k (always 8, hard-coded)

  char* w = (char*)d_ws;
  float*          Hq   = (float*)(w);                       //  1,048,576 B
  float*          Hm   = (float*)(w + 1048576);             // 51,200,000 B
  unsigned short* Hqb  = (unsigned short*)(w + 52248576);   //    524,288 B
  unsigned short* Hmb  = (unsigned short*)(w + 52772864);   // 25,624,576 B (padded to 50048 rows)
  float2*         auxq = (float2*)(w + 78397440);           //      8,192 B
  float2*         auxm = (float2*)(w + 78405632);           //    400,384 B (padded)
  float*          cs   = (float*)(w + 78806016);            //  1,310,720 B
  int*            cix  = (int*)(w + 80116736);              //  1,310,720 B -> 81,427,456 total

  // Wt bf16 planes alias the cand_s region (dead until score_kernel writes it)
  unsigned short* Wt1 = (unsigned short*)(w + 78806016);    // 3 x 131,072 B
  unsigned short* Wt2 = Wt1 + DIM * DIM;
  unsigned short* Wt3 = Wt2 + DIM * DIM;

  wsplit_kernel<<<DIM, DIM, 0, stream>>>(W, Wt1, Wt2, Wt3);
  transform_kernel<<<(B_Q + TROWS - 1) / TROWS, 1024, 0, stream>>>(Q, B_Q, Wt1, Wt2, Wt3, bv, Hq, Hqb, auxq);
  transform_kernel<<<(N_M + TROWS - 1) / TROWS, 1024, 0, stream>>>(M, N_M, Wt1, Wt2, Wt3, bv, Hm, Hmb, auxm);
  score_kernel<<<dim3(NCHUNK, B_Q / 32), 256, 0, stream>>>(Hqb, Hmb, auxq, auxm, cs, cix);
  finalize_kernel<<<B_Q, 256, 0, stream>>>(Hq, Hm, masks, cs, cix,
                                           (float*)d_out, (float*)d_out + (size_t)B_Q * KSEL);
}

// Round 2
// 397.944 us; speedup vs baseline: 78.4637x; 78.4637x over previous
//
#include <hip/hip_runtime.h>
#include <hip/hip_bf16.h>
#include <math.h>
#include <float.h>

#define B_Q   1024
#define N_M   50000
#define DIM   256
#define ATOMS 200
#define KSEL  8
#define NCHUNK 40
#define CHUNK  1250       // N_M / NCHUNK exactly
#define MT    128
#define NMT   10          // CHUNK/MT rounded up
#define CPC   8           // candidates kept per (query, chunk)
#define NC    (NCHUNK * CPC)   // 320 candidates per query
#define T16   16          // finalize rescore set
#define TROWS 64          // transform rows per block
#define APX   264         // A-plane LDS row stride in bf16 elems (528B, 16B-aligned)

typedef __attribute__((ext_vector_type(8))) short bf16x8;
typedef __attribute__((ext_vector_type(4))) float f32x4;

static __device__ inline unsigned short f2bf(float f) {
  __hip_bfloat16 h = __float2bfloat16(f);   // RNE
  return *reinterpret_cast<unsigned short*>(&h);
}

// RNE 3-way split (one-time W prep): x ~= s1+s2+s3, residual <= 2^-27 |x|
static __device__ inline void split3(float x, unsigned short& s1,
                                     unsigned short& s2, unsigned short& s3) {
  __hip_bfloat16 b1 = __float2bfloat16(x);
  float f1 = __bfloat162float(b1);
  float r1 = x - f1;
  __hip_bfloat16 b2 = __float2bfloat16(r1);
  float f2 = __bfloat162float(b2);
  __hip_bfloat16 b3 = __float2bfloat16(r1 - f2);
  s1 = *reinterpret_cast<unsigned short*>(&b1);
  s2 = *reinterpret_cast<unsigned short*>(&b2);
  s3 = *reinterpret_cast<unsigned short*>(&b3);
}

// Truncation 3-way split (hot path, 2 VALU/tier): residual <= 2^-24 |x|.
// x - trunc16(x) is exact (Sterbenz). Combined with RNE W tiers, dropped
// cross terms ~1e-7 rel — under the 5e-7 z-error budget.
static __device__ inline void split3t(float x, unsigned short& s1,
                                      unsigned short& s2, unsigned short& s3) {
  const unsigned u = __float_as_uint(x);
  s1 = (unsigned short)(u >> 16);
  const float f1 = __uint_as_float(u & 0xffff0000u);
  const float r1 = x - f1;                       // exact
  const unsigned v = __float_as_uint(r1);
  s2 = (unsigned short)(v >> 16);
  const float f2 = __uint_as_float(v & 0xffff0000u);
  const float r2 = r1 - f2;                      // exact
  s3 = (unsigned short)(__float_as_uint(r2) >> 16);
}

// fp32 tanh via HW v_exp_f32 (~1ulp): rel err ~1.5e-7.
static __device__ inline float tanh32(float z) {
  float tz = fabsf(z) * 2.885390082f;           // 2|z|*log2(e)
  tz = fminf(tz, 120.f);
  const float E = __builtin_amdgcn_exp2f(tz);   // e^{2|z|}
  const float T = 1.f - 2.f / (E + 1.f);
  return (z >= 0.f) ? T : -T;
}

// ---------------------------------------------------------------------------
// W pre-split: Wt planes [n][k] (transposed) as bf16 triple. 256x256, tiny.
// ---------------------------------------------------------------------------
__global__ __launch_bounds__(256) void wsplit_kernel(
    const float* __restrict__ W,
    unsigned short* __restrict__ Wt1, unsigned short* __restrict__ Wt2,
    unsigned short* __restrict__ Wt3)
{
  const int n = blockIdx.x;
  const int k = threadIdx.x;
  unsigned short s1, s2, s3;
  split3(W[(size_t)k * DIM + n], s1, s2, s3);
  Wt1[(size_t)n * DIM + k] = s1;
  Wt2[(size_t)n * DIM + k] = s2;
  Wt3[(size_t)n * DIM + k] = s3;
}

// ---------------------------------------------------------------------------
// Transform: H = to_poincare(X @ W + b); X@W via bf16 MFMA, 3-way Dekker
// split (6 product orders) chained into one fp32 accumulator per m-subtile.
// Block = 64 rows x 1024 threads (16 waves); wave w owns output cols
// [16w,16w+16): Wt is read ONCE per block (24 b128 loads/wave, explicit
// ks+1 double-buffer), A-planes staged in LDS (101KB, truncation splits,
// b128 writes). Per ks: 3 B-loads + 12 A ds_reads + 24 MFMA.
// MFMA layouts (HW-verified here through 4 passing rounds):
// A[m=lane&15][k=quad*8+j], B[n=lane&15][k=quad*8+j], D col=lane&15
// row=quad*4+reg. Epilogue fp32: tanh, 2-level row-norm reduce, scale, aux.
// ---------------------------------------------------------------------------
__global__ __launch_bounds__(1024) void transform_kernel(
    const float* __restrict__ X, int nrows,
    const unsigned short* __restrict__ Wt1, const unsigned short* __restrict__ Wt2,
    const unsigned short* __restrict__ Wt3, const float* __restrict__ bvec,
    float* __restrict__ H, unsigned short* __restrict__ Hb,
    float2* __restrict__ aux)
{
  __shared__ __align__(16) unsigned short X1s[TROWS * APX];
  __shared__ __align__(16) unsigned short X2s[TROWS * APX];
  __shared__ __align__(16) unsigned short X3s[TROWS * APX];
  __shared__ float red[16][TROWS];
  __shared__ float sArr[TROWS];

  const int t    = threadIdx.x;
  const int lane = t & 63;
  const int wave = t >> 6;
  const int row0 = blockIdx.x * TROWS;

  // stage + split X tile [64][256]: thread owns (row r, 16 cols at c0)
  {
    const int r  = t >> 4;
    const int c0 = (t & 15) * 16;
    int gr = row0 + r; if (gr >= nrows) gr = nrows - 1;   // clamp (stores guarded)
    const float4* src = (const float4*)(X + (size_t)gr * DIM + c0);
    bf16x8 p1[2], p2[2], p3[2];
#pragma unroll
    for (int half = 0; half < 2; ++half) {
#pragma unroll
      for (int v = 0; v < 2; ++v) {
        const float4 x4 = src[half * 2 + v];
        const float xv[4] = {x4.x, x4.y, x4.z, x4.w};
#pragma unroll
        for (int i = 0; i < 4; ++i) {
          unsigned short s1, s2, s3;
          split3t(xv[i], s1, s2, s3);
          p1[half][v * 4 + i] = (short)s1;
          p2[half][v * 4 + i] = (short)s2;
          p3[half][v * 4 + i] = (short)s3;
        }
      }
      *(bf16x8*)(X1s + r * APX + c0 + half * 8) = p1[half];
      *(bf16x8*)(X2s + r * APX + c0 + half * 8) = p2[half];
      *(bf16x8*)(X3s + r * APX + c0 + half * 8) = p3[half];
    }
  }
  __syncthreads();

  const int lx   = lane & 15;    // A row m / B col n / D col
  const int quad = lane >> 4;    // k-group / D row-quad
  const int n0   = wave * 16;    // this wave's output col-tile

  f32x4 acc[4];
#pragma unroll
  for (int ms = 0; ms < 4; ++ms) { acc[ms][0] = 0.f; acc[ms][1] = 0.f; acc[ms][2] = 0.f; acc[ms][3] = 0.f; }

  const size_t brow = (size_t)(n0 + lx) * DIM + quad * 8;
  bf16x8 b1c = *(const bf16x8*)(Wt1 + brow);
  bf16x8 b2c = *(const bf16x8*)(Wt2 + brow);
  bf16x8 b3c = *(const bf16x8*)(Wt3 + brow);

#pragma unroll
  for (int ks = 0; ks < 8; ++ks) {
    bf16x8 b1n, b2n, b3n;
    if (ks < 7) {                       // prefetch next k-step's B
      const size_t nb = brow + (ks + 1) * 32;
      b1n = *(const bf16x8*)(Wt1 + nb);
      b2n = *(const bf16x8*)(Wt2 + nb);
      b3n = *(const bf16x8*)(Wt3 + nb);
    }
    const int ko = ks * 32 + quad * 8;
#pragma unroll
    for (int ms = 0; ms < 4; ++ms) {
      const int ar = (ms * 16 + lx) * APX + ko;
      const bf16x8 a1 = *(const bf16x8*)(X1s + ar);
      const bf16x8 a2 = *(const bf16x8*)(X2s + ar);
      const bf16x8 a3 = *(const bf16x8*)(X3s + ar);
      acc[ms] = __builtin_amdgcn_mfma_f32_16x16x32_bf16(a1, b1c, acc[ms], 0, 0, 0);
      acc[ms] = __builtin_amdgcn_mfma_f32_16x16x32_bf16(a1, b2c, acc[ms], 0, 0, 0);
      acc[ms] = __builtin_amdgcn_mfma_f32_16x16x32_bf16(a2, b1c, acc[ms], 0, 0, 0);
      acc[ms] = __builtin_amdgcn_mfma_f32_16x16x32_bf16(a1, b3c, acc[ms], 0, 0, 0);
      acc[ms] = __builtin_amdgcn_mfma_f32_16x16x32_bf16(a2, b2c, acc[ms], 0, 0, 0);
      acc[ms] = __builtin_amdgcn_mfma_f32_16x16x32_bf16(a3, b1c, acc[ms], 0, 0, 0);
    }
    b1c = b1n; b2c = b2n; b3c = b3n;
  }

  // bias + tanh: lane holds rows ms*16+quad*4+r, col n0+lx (bias col-constant)
  const float bb = bvec[n0 + lx];
  float h[4][4];
#pragma unroll
  for (int ms = 0; ms < 4; ++ms)
#pragma unroll
    for (int r = 0; r < 4; ++r)
      h[ms][r] = tanh32(acc[ms][r] + bb);

  // row-norm partial over this wave's 16 cols (shuffle over lx)
  float p[4][4];
#pragma unroll
  for (int ms = 0; ms < 4; ++ms)
#pragma unroll
    for (int r = 0; r < 4; ++r) p[ms][r] = h[ms][r] * h[ms][r];
#pragma unroll
  for (int off = 1; off < 16; off <<= 1)
#pragma unroll
    for (int ms = 0; ms < 4; ++ms)
#pragma unroll
      for (int r = 0; r < 4; ++r) p[ms][r] += __shfl_xor(p[ms][r], off);
  if (lx == 0)
#pragma unroll
    for (int ms = 0; ms < 4; ++ms)
#pragma unroll
      for (int r = 0; r < 4; ++r) red[wave][ms * 16 + quad * 4 + r] = p[ms][r];
  __syncthreads();

  if (t < TROWS) {
    float nsq = 0.f;
#pragma unroll
    for (int w = 0; w < 16; ++w) nsq += red[w][t];
    const float nrm = sqrtf(nsq);
    sArr[t] = (nrm > 0.95f) ? (0.95f / nrm) : 1.f;
  }
  __syncthreads();

  float u[4][4];
#pragma unroll
  for (int ms = 0; ms < 4; ++ms)
#pragma unroll
    for (int r = 0; r < 4; ++r) {
      const float sc = sArr[ms * 16 + quad * 4 + r];
      u[ms][r] = h[ms][r] * sc;
      p[ms][r] = u[ms][r] * u[ms][r];
    }
#pragma unroll
  for (int off = 1; off < 16; off <<= 1)
#pragma unroll
    for (int ms = 0; ms < 4; ++ms)
#pragma unroll
      for (int r = 0; r < 4; ++r) p[ms][r] += __shfl_xor(p[ms][r], off);
  if (lx == 0)
#pragma unroll
    for (int ms = 0; ms < 4; ++ms)
#pragma unroll
      for (int r = 0; r < 4; ++r) red[wave][ms * 16 + quad * 4 + r] = p[ms][r];

  // stores: H fp32 + Hb bf16 (guarded rows)
#pragma unroll
  for (int ms = 0; ms < 4; ++ms)
#pragma unroll
    for (int r = 0; r < 4; ++r) {
      const int grow = row0 + ms * 16 + quad * 4 + r;
      if (grow < nrows) {
        H[(size_t)grow * DIM + n0 + lx]  = u[ms][r];
        Hb[(size_t)grow * DIM + n0 + lx] = f2bf(u[ms][r]);
      }
    }
  __syncthreads();
  if (t < TROWS) {
    const int grow = row0 + t;
    if (grow < nrows) {
      float ysq = 0.f;
#pragma unroll
      for (int w = 0; w < 16; ++w) ysq += red[w][t];
      aux[grow] = make_float2(ysq, 1.f / (1.f - ysq));
    }
  }
}

// ---------------------------------------------------------------------------
// Score (MFMA), v3: barrier-free independent waves, FULLY SCALARIZED state.
// Round-1 post-mortem: local arrays (tS[8][3]/tI[8][3], b0[4]/b1[4]) were
// demoted to scratch under __launch_bounds__(256,3) -> 133 GB of scratch
// writes/dispatch, 31 ms. Fix: every piece of per-lane state is a NAMED
// variable (24 packed u64 top-3 regs, 8 named B fragments, 4 named accs),
// manipulated through token-pasting macros so promotion is trivial; the
// occupancy bound is dropped (natural ~140 VGPR -> 3 waves/SIMD).
// Algorithm unchanged vs v2: block = 32 queries x 1 chunk, 4 waves; each
// wave owns m-rows {mt*128 + wave*32 + 0..31}; scores go straight from the
// accumulator into per-lane sorted top-3 per query-row (packed u64
// score<<32|idx: score >= 0 so uint compare preserves order; idx < 2^17).
// No Sc LDS round-trip, no per-mtile barriers. Chunk-tail cols masked.
// Safety: global-top-8 entry lost only if >=3 of the top-8 land in one
// lane's ~20-value subset (E ~ 5e-6 overall). End: per-wave 16-lane u64
// butterfly -> wave top-8/query -> one barrier -> 8-thread cross-wave
// merge -> exact per-(query,chunk) top-8. fp64 rescore later fixes order.
// ---------------------------------------------------------------------------
__global__ __launch_bounds__(256) void score_kernel(
    const unsigned short* __restrict__ Hqb, const unsigned short* __restrict__ Hmb,
    const float2* __restrict__ auxq, const float2* __restrict__ auxm,
    float* __restrict__ cand_s, int* __restrict__ cand_i)
{
  __shared__ __align__(16) unsigned short Afs[16 * 64 * 8]; // 16 KB, frag-order
  __shared__ unsigned long long wtop[4][32][CPC];           // 8 KB

  const int t    = threadIdx.x;
  const int lane = t & 63;
  const int wave = t >> 6;
  const int q0   = blockIdx.y * 32;
  const int c    = blockIdx.x;
  const int mbase = c * CHUNK;
  const int lx   = lane & 15;
  const int quad = lane >> 4;

  // stage A fragments into LDS (slot = ks*2+qs; each wave stages 4 slots)
#pragma unroll
  for (int i = 0; i < 4; ++i) {
    const int sl = wave * 4 + i;
    const int ks = sl >> 1, qs = sl & 1;
    const bf16x8 a = *(const bf16x8*)(Hqb + (size_t)(q0 + qs * 16 + lx) * DIM + ks * 32 + quad * 8);
    *(bf16x8*)(Afs + ((size_t)sl * 64 + lane) * 8) = a;
  }
  // per-row query norms (row = qs*4+r; rows 0-3 -> qs=0, rows 4-7 -> qs=1)
  const float xq0 = auxq[q0 +      quad * 4 + 0].x;
  const float xq1 = auxq[q0 +      quad * 4 + 1].x;
  const float xq2 = auxq[q0 +      quad * 4 + 2].x;
  const float xq3 = auxq[q0 +      quad * 4 + 3].x;
  const float xq4 = auxq[q0 + 16 + quad * 4 + 0].x;
  const float xq5 = auxq[q0 + 16 + quad * 4 + 1].x;
  const float xq6 = auxq[q0 + 16 + quad * 4 + 2].x;
  const float xq7 = auxq[q0 + 16 + quad * 4 + 3].x;
  __syncthreads();          // the ONLY pre-merge barrier

  // 24 named packed top-3 regs (sorted ascending: a <= b <= c)
  unsigned long long t0a=~0ULL,t0b=~0ULL,t0c=~0ULL, t1a=~0ULL,t1b=~0ULL,t1c=~0ULL;
  unsigned long long t2a=~0ULL,t2b=~0ULL,t2c=~0ULL, t3a=~0ULL,t3b=~0ULL,t3c=~0ULL;
  unsigned long long t4a=~0ULL,t4b=~0ULL,t4c=~0ULL, t5a=~0ULL,t5b=~0ULL,t5c=~0ULL;
  unsigned long long t6a=~0ULL,t6b=~0ULL,t6c=~0ULL, t7a=~0ULL,t7b=~0ULL,t7c=~0ULL;

  const int col0 = wave * 32 + lx;   // within-128-tile column, ms=0

// one MFMA k-step: A slots (KS*2+0 / KS*2+1) x named B frags
#define KSTEP(KS, BA, BB) do {                                                        \
    const bf16x8 a0_ = *(const bf16x8*)(Afs + (((KS) * 2 + 0) * 64 + lane) * 8);      \
    const bf16x8 a1_ = *(const bf16x8*)(Afs + (((KS) * 2 + 1) * 64 + lane) * 8);      \
    acc00 = __builtin_amdgcn_mfma_f32_16x16x32_bf16(a0_, BA, acc00, 0, 0, 0);         \
    acc01 = __builtin_amdgcn_mfma_f32_16x16x32_bf16(a0_, BB, acc01, 0, 0, 0);         \
    acc10 = __builtin_amdgcn_mfma_f32_16x16x32_bf16(a1_, BA, acc10, 0, 0, 0);         \
    acc11 = __builtin_amdgcn_mfma_f32_16x16x32_bf16(a1_, BB, acc11, 0, 0, 0);         \
  } while (0)

// score one accumulator element -> sorted top-3 insert (all tokens named vars)
#define SCORE1(ACC, R, YM, RO, OK, GI, XQ, T0, T1, T2) do {                           \
    const float sv_ = fmaxf(fmaf(-2.f, (ACC)[R], (XQ) + (YM)), 0.f) * (RO);           \
    if (OK) {                                                                          \
      const unsigned long long pk_ =                                                   \
        (((unsigned long long)__float_as_uint(sv_)) << 32) | (unsigned int)(GI);       \
      if (pk_ < T2) {                                                                  \
        T2 = pk_;                                                                      \
        if (T2 < T1) { const unsigned long long x_ = T1; T1 = T2; T2 = x_; }           \
        if (T1 < T0) { const unsigned long long x_ = T0; T0 = T1; T1 = x_; }           \
      }                                                                                \
    }                                                                                  \
  } while (0)

  for (int mt = 0; mt < NMT; ++mt) {
    const int mrow0 = mbase + mt * MT + wave * 32;
    const int rem   = CHUNK - mt * MT;       // >= 98; only mt=9 masks anything
    const bool ok0  = col0 < rem;
    const bool ok1  = col0 + 16 < rem;

    f32x4 acc00 = {0.f, 0.f, 0.f, 0.f};
    f32x4 acc01 = {0.f, 0.f, 0.f, 0.f};
    f32x4 acc10 = {0.f, 0.f, 0.f, 0.f};
    f32x4 acc11 = {0.f, 0.f, 0.f, 0.f};

    const float2 aux0 = auxm[mrow0 + lx];
    const float2 aux1 = auxm[mrow0 + 16 + lx];

    const unsigned short* B0p = Hmb + (size_t)(mrow0 + lx)      * DIM + quad * 8;
    const unsigned short* B1p = Hmb + (size_t)(mrow0 + 16 + lx) * DIM + quad * 8;

    // batch 1: ks 0..3 (8 named frags in flight)
    bf16x8 bA0 = *(const bf16x8*)(B0p + 0 * 32);
    bf16x8 bA1 = *(const bf16x8*)(B0p + 1 * 32);
    bf16x8 bA2 = *(const bf16x8*)(B0p + 2 * 32);
    bf16x8 bA3 = *(const bf16x8*)(B0p + 3 * 32);
    bf16x8 bB0 = *(const bf16x8*)(B1p + 0 * 32);
    bf16x8 bB1 = *(const bf16x8*)(B1p + 1 * 32);
    bf16x8 bB2 = *(const bf16x8*)(B1p + 2 * 32);
    bf16x8 bB3 = *(const bf16x8*)(B1p + 3 * 32);
    KSTEP(0, bA0, bB0);
    KSTEP(1, bA1, bB1);
    KSTEP(2, bA2, bB2);
    KSTEP(3, bA3, bB3);

    // batch 2: ks 4..7 (reuse the same named frags)
    bA0 = *(const bf16x8*)(B0p + 4 * 32);
    bA1 = *(const bf16x8*)(B0p + 5 * 32);
    bA2 = *(const bf16x8*)(B0p + 6 * 32);
    bA3 = *(const bf16x8*)(B0p + 7 * 32);
    bB0 = *(const bf16x8*)(B1p + 4 * 32);
    bB1 = *(const bf16x8*)(B1p + 5 * 32);
    bB2 = *(const bf16x8*)(B1p + 6 * 32);
    bB3 = *(const bf16x8*)(B1p + 7 * 32);
    KSTEP(4, bA0, bB0);
    KSTEP(5, bA1, bB1);
    KSTEP(6, bA2, bB2);
    KSTEP(7, bA3, bB3);

    // scores straight from accumulators -> per-lane top-3 inserts
    const float ym0 = aux0.x, ro0 = aux0.y;
    const float ym1 = aux1.x, ro1 = aux1.y;
    const int   gi0 = mrow0 + lx;
    const int   gi1 = mrow0 + 16 + lx;

    SCORE1(acc00, 0, ym0, ro0, ok0, gi0, xq0, t0a, t0b, t0c);
    SCORE1(acc00, 1, ym0, ro0, ok0, gi0, xq1, t1a, t1b, t1c);
    SCORE1(acc00, 2, ym0, ro0, ok0, gi0, xq2, t2a, t2b, t2c);
    SCORE1(acc00, 3, ym0, ro0, ok0, gi0, xq3, t3a, t3b, t3c);
    SCORE1(acc01, 0, ym1, ro1, ok1, gi1, xq0, t0a, t0b, t0c);
    SCORE1(acc01, 1, ym1, ro1, ok1, gi1, xq1, t1a, t1b, t1c);
    SCORE1(acc01, 2, ym1, ro1, ok1, gi1, xq2, t2a, t2b, t2c);
    SCORE1(acc01, 3, ym1, ro1, ok1, gi1, xq3, t3a, t3b, t3c);
    SCORE1(acc10, 0, ym0, ro0, ok0, gi0, xq4, t4a, t4b, t4c);
    SCORE1(acc10, 1, ym0, ro0, ok0, gi0, xq5, t5a, t5b, t5c);
    SCORE1(acc10, 2, ym0, ro0, ok0, gi0, xq6, t6a, t6b, t6c);
    SCORE1(acc10, 3, ym0, ro0, ok0, gi0, xq7, t7a, t7b, t7c);
    SCORE1(acc11, 0, ym1, ro1, ok1, gi1, xq4, t4a, t4b, t4c);
    SCORE1(acc11, 1, ym1, ro1, ok1, gi1, xq5, t5a, t5b, t5c);
    SCORE1(acc11, 2, ym1, ro1, ok1, gi1, xq6, t6a, t6b, t6c);
    SCORE1(acc11, 3, ym1, ro1, ok1, gi1, xq7, t7a, t7b, t7c);
  }

#undef KSTEP
#undef SCORE1

  // per-wave extraction: per query-row, 16 lanes x top-3 -> wave top-8.
  // (quads handle 4 query-rows in parallel; shfl offsets 1..8 stay in-quad)
#define EXTRACT_ROW(WIDX, T0, T1, T2) do {                                            \
    unsigned long long p0 = T0, p1 = T1, p2 = T2;                                     \
    for (int rd = 0; rd < CPC; ++rd) {                                                \
      unsigned long long lm = (p0 < p1) ? p0 : p1;                                    \
      lm = (p2 < lm) ? p2 : lm;                                                       \
      unsigned long long gm = lm;                                                     \
      for (int off = 1; off < 16; off <<= 1) {                                        \
        const unsigned long long o = __shfl_xor(gm, off);                             \
        gm = (o < gm) ? o : gm;                                                       \
      }                                                                               \
      if      (p0 == gm) p0 = ~0ULL;                                                  \
      else if (p1 == gm) p1 = ~0ULL;                                                  \
      else if (p2 == gm) p2 = ~0ULL;                                                  \
      if (lx == 0) wtop[wave][WIDX][rd] = gm;                                         \
    }                                                                                 \
  } while (0)

  EXTRACT_ROW(quad * 4 + 0,      t0a, t0b, t0c);
  EXTRACT_ROW(quad * 4 + 1,      t1a, t1b, t1c);
  EXTRACT_ROW(quad * 4 + 2,      t2a, t2b, t2c);
  EXTRACT_ROW(quad * 4 + 3,      t3a, t3b, t3c);
  EXTRACT_ROW(16 + quad * 4 + 0, t4a, t4b, t4c);
  EXTRACT_ROW(16 + quad * 4 + 1, t5a, t5b, t5c);
  EXTRACT_ROW(16 + quad * 4 + 2, t6a, t6b, t6c);
  EXTRACT_ROW(16 + quad * 4 + 3, t7a, t7b, t7c);
#undef EXTRACT_ROW
  __syncthreads();

  // cross-wave merge: 8 threads per query, 4 waves x 8 -> top-8 -> cand
  {
    const int qr = t >> 3;        // 0..31
    const int sp = t & 7;
    unsigned long long v0 = wtop[0][qr][sp];
    unsigned long long v1 = wtop[1][qr][sp];
    unsigned long long v2 = wtop[2][qr][sp];
    unsigned long long v3 = wtop[3][qr][sp];
    const size_t cbase = ((size_t)(q0 + qr) * NCHUNK + c) * CPC;
    for (int rd = 0; rd < CPC; ++rd) {
      unsigned long long lm = (v0 < v1) ? v0 : v1;
      const unsigned long long l2 = (v2 < v3) ? v2 : v3;
      lm = (l2 < lm) ? l2 : lm;
      unsigned long long gm = lm;
#pragma unroll
      for (int off = 1; off < 8; off <<= 1) {
        const unsigned long long o = __shfl_xor(gm, off);
        gm = (o < gm) ? o : gm;
      }
      if      (v0 == gm) v0 = ~0ULL;
      else if (v1 == gm) v1 = ~0ULL;
      else if (v2 == gm) v2 = ~0ULL;
      else if (v3 == gm) v3 = ~0ULL;
      if (sp == 0) {
        cand_s[cbase + rd] = __uint_as_float((unsigned int)(gm >> 32));
        cand_i[cbase + rd] = (int)(unsigned int)(gm & 0xffffffffu);
      }
    }
  }
}

// ---------------------------------------------------------------------------
// Finalize: per query, 256 threads (4 waves): parallel candidate merge
// 320 -> 4x16 -> top-16 (fp32 score, idx tie-break), fp64 rescore (4 cands
// per wave) -> exact top-8 order, softmax, parallel mask gather.
// ---------------------------------------------------------------------------
__global__ __launch_bounds__(256) void finalize_kernel(
    const float* __restrict__ Hq, const float* __restrict__ Hm,
    const float* __restrict__ masks,
    const float* __restrict__ cand_s, const int* __restrict__ cand_i,
    float* __restrict__ outW, float* __restrict__ outH)
{
  const int q    = blockIdx.x;
  const int t    = threadIdx.x;
  const int lane = t & 63;
  const int wave = t >> 6;

  __shared__ unsigned long long wtop[4][T16];
  __shared__ int    selIdx[T16];
  __shared__ double dArr[T16];
  __shared__ int    fin_i[KSEL];
  __shared__ double fin_d[KSEL];
  __shared__ double ew[KSEL];

  // phase 1: each wave takes 80 candidates -> its top-16 (indices unique)
  {
    const size_t base = (size_t)q * NC + (size_t)wave * (NC / 4);
    unsigned long long pk[2];
#pragma unroll
    for (int s = 0; s < 2; ++s) {
      const int c = lane + 64 * s;
      pk[s] = (c < NC / 4)
        ? ((((unsigned long long)__float_as_uint(cand_s[base + c])) << 32) | (unsigned int)cand_i[base + c])
        : ~0ULL;
    }
    for (int r = 0; r < T16; ++r) {
      unsigned long long lm = (pk[0] < pk[1]) ? pk[0] : pk[1];
      unsigned long long gm = lm;
#pragma unroll
      for (int off = 1; off < 64; off <<= 1) {
        unsigned long long o = __shfl_xor(gm, off);
        gm = (o < gm) ? o : gm;
      }
      bool done = false;
#pragma unroll
      for (int s = 0; s < 2; ++s) if (!done && pk[s] == gm) { pk[s] = ~0ULL; done = true; }
      if (lane == 0) wtop[wave][r] = gm;
    }
  }
  __syncthreads();

  // phase 2: wave 0 merges 64 -> global top-16
  if (wave == 0) {
    unsigned long long v = wtop[lane >> 4][lane & 15];
    for (int r = 0; r < T16; ++r) {
      unsigned long long gm = v;
#pragma unroll
      for (int off = 1; off < 64; off <<= 1) {
        unsigned long long o = __shfl_xor(gm, off);
        gm = (o < gm) ? o : gm;
      }
      if (v == gm) v = ~0ULL;
      if (lane == 0) selIdx[r] = (int)(unsigned int)(gm & 0xffffffffULL);
    }
  }
  __syncthreads();

  // phase 3: fp64 rescore, 4 candidates per wave
  const float4 q4 = *(const float4*)(Hq + (size_t)q * DIM + 4 * lane);
  double xp_ = (double)q4.x * q4.x + (double)q4.y * q4.y + (double)q4.z * q4.z + (double)q4.w * q4.w;
#pragma unroll
  for (int off = 1; off < 64; off <<= 1) xp_ += __shfl_xor(xp_, off);
  const double xsq = xp_;

  for (int r = wave; r < T16; r += 4) {
    const int cidx = selIdx[r];
    const float4 m4 = *(const float4*)(Hm + (size_t)cidx * DIM + 4 * lane);
    double dp = (double)q4.x * m4.x + (double)q4.y * m4.y + (double)q4.z * m4.z + (double)q4.w * m4.w;
    double yp = (double)m4.x * m4.x + (double)m4.y * m4.y + (double)m4.z * m4.z + (double)m4.w * m4.w;
#pragma unroll
    for (int off = 1; off < 64; off <<= 1) { dp += __shfl_xor(dp, off); yp += __shfl_xor(yp, off); }
    if (lane == 0) {
      double diff = xsq + yp - 2.0 * dp; if (diff < 0.0) diff = 0.0;
      double den = (1.0 - xsq) * (1.0 - yp);
      double arg = 1.0 + 2.0 * diff / (den + 1e-8);
      const double lo = 1.0 + 1e-6;
      if (arg < lo) arg = lo;
      dArr[r] = log(arg + sqrt(arg * arg - 1.0));   // arccosh
    }
  }
  __syncthreads();

  // phase 4: exact rank (dist, idx) -> top-8, softmax
  if (t < T16) {
    const double dj = dArr[t]; const int ij = selIdx[t];
    int rank = 0;
#pragma unroll
    for (int i = 0; i < T16; ++i)
      rank += (dArr[i] < dj || (dArr[i] == dj && selIdx[i] < ij)) ? 1 : 0;
    if (rank < KSEL) { fin_d[rank] = dj; fin_i[rank] = ij; }
  }
  __syncthreads();
  if (t < KSEL) ew[t] = exp(fin_d[0] - fin_d[t]);
  __syncthreads();
  if (t < KSEL) {
    double ssum = 0.0;
#pragma unroll
    for (int i = 0; i < KSEL; ++i) ssum += ew[i];
    outW[(size_t)q * KSEL + t] = (float)(ew[t] / ssum);
  }

  // phase 5: mask gather, 32 threads per output row
  const int g  = t >> 5;
  const int l0 = t & 31;
  const int row = fin_i[g];
  for (int l = l0; l < ATOMS; l += 32)
    outH[((size_t)q * KSEL + g) * ATOMS + l] = masks[(size_t)row * ATOMS + l];
}

// ---------------------------------------------------------------------------
extern "C" void kernel_launch(void* const* d_in, const int* in_sizes, int n_in,
                              void* d_out, int out_size, void* d_ws, size_t ws_size,
                              hipStream_t stream) {
  const float* Q     = (const float*)d_in[0];   // [1024,256]
  const float* M     = (const float*)d_in[1];   // [50000,256]
  const float* masks = (const float*)d_in[2];   // [50000,200]
  const float* W     = (const float*)d_in[3];   // [256,256]
  const float* bv    = (const float*)d_in[4];   // [256]
  // d_in[5] = k (always 8, hard-coded)

  char* w = (char*)d_ws;
  float*          Hq   = (float*)(w);                       //  1,048,576 B
  float*          Hm   = (float*)(w + 1048576);             // 51,200,000 B
  unsigned short* Hqb  = (unsigned short*)(w + 52248576);   //    524,288 B
  unsigned short* Hmb  = (unsigned short*)(w + 52772864);   // 25,624,576 B (padded to 50048 rows)
  float2*         auxq = (float2*)(w + 78397440);           //      8,192 B
  float2*         auxm = (float2*)(w + 78405632);           //    400,384 B (padded)
  float*          cs   = (float*)(w + 78806016);            //  1,310,720 B
  int*            cix  = (int*)(w + 80116736);              //  1,310,720 B -> 81,427,456 total

  // Wt bf16 planes alias the cand_s region (dead until score_kernel writes it)
  unsigned short* Wt1 = (unsigned short*)(w + 78806016);    // 3 x 131,072 B
  unsigned short* Wt2 = Wt1 + DIM * DIM;
  unsigned short* Wt3 = Wt2 + DIM * DIM;

  wsplit_kernel<<<DIM, DIM, 0, stream>>>(W, Wt1, Wt2, Wt3);
  transform_kernel<<<(B_Q + TROWS - 1) / TROWS, 1024, 0, stream>>>(Q, B_Q, Wt1, Wt2, Wt3, bv, Hq, Hqb, auxq);
  transform_kernel<<<(N_M + TROWS - 1) / TROWS, 1024, 0, stream>>>(M, N_M, Wt1, Wt2, Wt3, bv, Hm, Hmb, auxm);
  score_kernel<<<dim3(NCHUNK, B_Q / 32), 256, 0, stream>>>(Hqb, Hmb, auxq, auxm, cs, cix);
  finalize_kernel<<<B_Q, 256, 0, stream>>>(Hq, Hm, masks, cs, cix,
                                           (float*)d_out, (float*)d_out + (size_t)B_Q * KSEL);
}